// Round 1
// 379.012 us; speedup vs baseline: 1.0062x; 1.0062x over previous
//
#include <hip/hip_runtime.h>

// StandardDeviationPooling: 4x4 windows, stride 2, VALID.
// in:  (64, 1024, 1024) fp32   out: (64, 511, 511) fp32
// std = sqrt(max(E[x^2] - E[x]^2, 0)), n = 16.
//
// R4: same separable rolling-window algorithm as R3, but the 33-phase
// rowpair loop is ROLLED (unroll-2 skeleton, #pragma unroll 1) instead of
// fully unrolled.
//  - Theory: R3's full unroll produced a ~16KB straight-line body whose
//    hoisted address/live ranges overflow the 128-VGPR cap -> scratch
//    spill round-trips (~3x parasitic VMEM traffic) + I$ streaming.
//    Kernel measured ~220us vs ~57us memory roofline (4x off).
//  - Double buffers are NAMED (A0/C0, A1/C1), never runtime-indexed
//    (runtime-indexed vector arrays go to scratch on hipcc).
//  - Skeleton: peeled phase t=0 (no emit, prefetch t=2), 15x unroll-2
//    steady iterations t=1..30 (prefetch t+2, emit row t0+t-1),
//    epilogue t=31,32 (no prefetch; t=32 emit guarded for strip 15).
//  - Everything else identical to R3: lane owns output cols {128w+2l,+1},
//    cross-lane pair via __shfl_down(.,1), lane-63 tail words prefetched
//    in the same pipeline, 16 strips x 32 output rows, 1024 blocks.

#define IN_H 1024
#define IN_W 1024
#define OUT_H 511
#define OUT_W 511
#define STRIPS 16
#define ORPS 32            // output rows per strip
#define PAIRS (ORPS + 1)   // rowpairs touched per strip (33)

__global__ __launch_bounds__(256, 4) void stdpool_kernel(
    const float* __restrict__ in, float* __restrict__ out) {
  const int tid = threadIdx.x;
  const int w = tid >> 6;  // wave 0..3
  const int l = tid & 63;  // lane 0..63
  const int strip = blockIdx.x;
  const int b = blockIdx.y;

  const int col0 = w * 256 + l * 4;      // first input col this lane loads
  const int o0 = w * 128 + l * 2;        // first output col this lane owns
  const bool has_o1 = (o0 + 1) < OUT_W;  // false only for w==3, l==63
  const bool tail = (l == 63) && has_o1; // lane 63 needs cols col0+4..5

  const int t0 = strip * ORPS;  // first rowpair index of this strip

  const float* __restrict__ src = in + (size_t)b * IN_H * IN_W + col0;
  float* __restrict__ dst = out + (size_t)b * OUT_H * OUT_W + o0;

  // Named double buffers: rowpair data (rows 2t, 2t+1), parity t&1.
  float4 A0, C0, A1, C1;
  float2 E00, E10, E01, E11;  // lane-63 tail words, same pipeline

  // preload rowpairs t=0 (buf0), t=1 (buf1); never needs clamping
  {
    const float* p = src + (size_t)(2 * t0) * IN_W;
    A0 = *(const float4*)p;
    C0 = *(const float4*)(p + IN_W);
    if (tail) {
      E00 = *(const float2*)(p + 4);
      E10 = *(const float2*)(p + IN_W + 4);
    }
    p += 2 * IN_W;
    A1 = *(const float4*)p;
    C1 = *(const float4*)(p + IN_W);
    if (tail) {
      E01 = *(const float2*)(p + 4);
      E11 = *(const float2*)(p + IN_W + 4);
    }
  }

  float Pp0, Pp1, Qp0, Qp1;  // previous rowpair window sums

  // One phase: consume buffer (Ab,Cb,E0b,E1b), prefetch rowpair T+2 into
  // the same buffer, emit output row t0+T-1.  All indexing static.
#define PHASE(T, Ab, Cb, E0b, E1b, DO_PF, DO_EMIT, LAST)                    \
  {                                                                         \
    const float4 a = Ab, c = Cb;                                            \
    const float2 e0 = E0b, e1 = E1b;                                        \
    if (DO_PF) { /* depth-2 prefetch into the slot just freed */            \
      int r = 2 * (t0 + (T) + 2);                                           \
      if (r > IN_H - 2) r = IN_H - 2; /* strip 15 tail: harmless re-read */ \
      const float* p = src + (size_t)r * IN_W;                              \
      Ab = *(const float4*)p;                                               \
      Cb = *(const float4*)(p + IN_W);                                      \
      if (tail) {                                                           \
        E0b = *(const float2*)(p + 4);                                      \
        E1b = *(const float2*)(p + IN_W + 4);                               \
      }                                                                     \
    }                                                                       \
    /* two-row-combined horizontal pair sums (values, squares) */           \
    const float c0 = (a.x + a.y) + (c.x + c.y);                             \
    const float c1 = (a.z + a.w) + (c.z + c.w);                             \
    const float d0 = fmaf(a.x, a.x, a.y * a.y) + fmaf(c.x, c.x, c.y * c.y); \
    const float d1 = fmaf(a.z, a.z, a.w * a.w) + fmaf(c.z, c.z, c.w * c.w); \
    /* neighbor lane's even pair (pair o0+2 lives in lane l+1) */           \
    float cn = __shfl_down(c0, 1, 64);                                      \
    float dn = __shfl_down(d0, 1, 64);                                      \
    if (tail) { /* lane 63: pair comes from the next wave's columns */      \
      cn = (e0.x + e0.y) + (e1.x + e1.y);                                   \
      dn = fmaf(e0.x, e0.x, e0.y * e0.y) + fmaf(e1.x, e1.x, e1.y * e1.y);   \
    }                                                                       \
    const float P0 = c0 + c1, P1 = c1 + cn; /* rowpair window sums */       \
    const float Q0 = d0 + d1, Q1 = d1 + dn;                                 \
    if (DO_EMIT) { /* emit output row t0+T-1 from rowpairs (T-1, T) */      \
      const int orow = t0 + (T)-1;                                          \
      if (!(LAST) || orow < OUT_H) { /* skips only strip 15 phantom 511 */  \
        const float inv = 1.0f / 16.0f;                                     \
        const float s0 = Pp0 + P0, s1 = Pp1 + P1;                           \
        const float q0 = Qp0 + Q0, q1 = Qp1 + Q1;                           \
        const float m0 = s0 * inv, m1 = s1 * inv;                           \
        const float v0 = fmaxf(fmaf(-m0, m0, q0 * inv), 0.0f);              \
        const float v1 = fmaxf(fmaf(-m1, m1, q1 * inv), 0.0f);              \
        float* op = dst + (size_t)orow * OUT_W;                             \
        op[0] = sqrtf(v0);              /* out rows only 4B-aligned -> */   \
        if (has_o1) op[1] = sqrtf(v1);  /* two dword stores, both dense */  \
      }                                                                     \
    }                                                                       \
    Pp0 = P0; Pp1 = P1; Qp0 = Q0; Qp1 = Q1;                                 \
  }

  // peeled first phase: t=0, prefetch t=2, no emit
  PHASE(0, A0, C0, E00, E10, true, false, false);

  // steady loop: t = 1..30 in 15 unroll-2 iterations; keep it ROLLED
#pragma unroll 1
  for (int t = 1; t <= 29; t += 2) {
    PHASE(t, A1, C1, E01, E11, true, true, false);      // odd t  -> buf1
    PHASE(t + 1, A0, C0, E00, E10, true, true, false);  // even t -> buf0
  }

  // epilogue: t=31 (buf1), t=32 (buf0, last-row guard); no prefetch
  PHASE(31, A1, C1, E01, E11, false, true, false);
  PHASE(32, A0, C0, E00, E10, false, true, true);
#undef PHASE
}

extern "C" void kernel_launch(void* const* d_in, const int* in_sizes, int n_in,
                              void* d_out, int out_size, void* d_ws,
                              size_t ws_size, hipStream_t stream) {
  const float* x = (const float*)d_in[0];
  float* out = (float*)d_out;

  dim3 block(256, 1, 1);
  dim3 grid(STRIPS, 64, 1);  // 16 row-strips x 64 images = 1024 blocks
  stdpool_kernel<<<grid, block, 0, stream>>>(x, out);
}